// Round 12
// baseline (67.597 us; speedup 1.0000x reference)
//
#include <hip/hip_runtime.h>

// NCC loss (B=2, C=1, 160^3 f32, 9^3 box window). Two passes + reduce.
// pass_zx: products + 4-wide sliding z-window in regs; per produced z the
//          x-window is applied via DOUBLE-BUFFERED bf16 LDS row staging
//          (one barrier per dz) -> fp8 bufA [b][z][y][f][x].
// pass_y : thin y-slide (4-wide, CHY=4) over xz-windowed fp8 rows + cc +
//          deterministic reduction.
// finalize: deterministic reduce.

typedef float floatx2 __attribute__((ext_vector_type(2)));

constexpr int W = 160, H = 160, D = 160;
constexpr int SLICE = W * H;
constexpr int NVOX  = W * H * D;
constexpr int BATCH = 2;
constexpr int FROW  = 5 * W;             // 800 B per (b,z,y) row-group
constexpr float RW  = 1.0f / 729.0f;

// pass_zx geometry
constexpr int TPB_ZX = 320;              // 8 rows x 40 x-groups
constexpr int ROWS_PB = 8;
constexpr int XGZ   = W / 4;             // 40
constexpr int CHZ   = 5, NCHZ = D / CHZ; // 32 z-chunks
constexpr int NTUP_ZX = BATCH * NCHZ * H;        // 10,240 (b,c,y) rows
constexpr int NBLK_ZX = NTUP_ZX / ROWS_PB;       // 1280
constexpr int LROW  = 168;               // 4 zero-pad | 160 | 4 zero-pad (bf16)

// pass_y geometry: 4-wide threads, CHY=4
constexpr int TPB_Y = 256;
constexpr int XGY4  = W / 4;             // 40
constexpr int CHY   = 4, NCHY = H / CHY; // 40
constexpr int NTH_Y = BATCH * D * NCHY * XGY4;   // 512,000
constexpr int NBLK_Y = NTH_Y / TPB_Y;            // 2000

// ---- fp8 / bf16 helpers --------------------------------------------------
__device__ inline unsigned int pk4(float a, float b, float c, float d) {
    unsigned int u = 0;
    u = __builtin_amdgcn_cvt_pk_fp8_f32(a, b, u, false);
    u = __builtin_amdgcn_cvt_pk_fp8_f32(c, d, u, true);
    return u;
}
__device__ inline void up4(unsigned int v, float* o) {
    floatx2 t;
    t = __builtin_amdgcn_cvt_pk_f32_fp8(v, false); o[0] = t[0]; o[1] = t[1];
    t = __builtin_amdgcn_cvt_pk_f32_fp8(v, true);  o[2] = t[0]; o[3] = t[1];
}
__device__ inline unsigned short f2bf(float f) {
    unsigned int u = __builtin_bit_cast(unsigned int, f);
    u += 0x7fffu + ((u >> 16) & 1u);
    return (unsigned short)(u >> 16);
}
__device__ inline unsigned int bfpack2(float lo, float hi) {
    return (unsigned int)f2bf(lo) | ((unsigned int)f2bf(hi) << 16);
}
__device__ inline float bflo(unsigned int u) {
    return __builtin_bit_cast(float, u << 16);
}
__device__ inline float bfhi(unsigned int u) {
    return __builtin_bit_cast(float, u & 0xffff0000u);
}

// ---- pass 1: z-window (regs) + x-window (dbuf bf16 LDS, 1 barrier/dz) ----
__global__ __launch_bounds__(TPB_ZX) void pass_zx(const float* __restrict__ I,
                                                  const float* __restrict__ J,
                                                  unsigned char* __restrict__ outA) {
    __shared__ unsigned short xw[2][ROWS_PB][5][LROW];   // 26,880 B

    int tid = threadIdx.x;
    int r  = tid / XGZ;                  // 0..7 row-in-block
    int xg = tid % XGZ;                  // 0..39
    int tuple = blockIdx.x * ROWS_PB + r;
    int y = tuple % H;
    int c = (tuple / H) % NCHZ;
    int b = tuple / (H * NCHZ);
    int x0 = xg * 4;
    const float* Ib = I + (size_t)b * NVOX + y * W + x0;
    const float* Jb = J + (size_t)b * NVOX + y * W + x0;
    unsigned char* ob = outA + ((size_t)b * D * H + y) * FROW + x0;

    // zero the halo pads once (both buffers)
    if (xg == 0) {
#pragma unroll
        for (int p = 0; p < 2; ++p)
#pragma unroll
            for (int f = 0; f < 5; ++f) {
                xw[p][r][f][0] = 0; xw[p][r][f][1] = 0;
                xw[p][r][f][2] = 0; xw[p][r][f][3] = 0;
            }
    }
    if (xg == XGZ - 1) {
#pragma unroll
        for (int p = 0; p < 2; ++p)
#pragma unroll
            for (int f = 0; f < 5; ++f) {
                xw[p][r][f][164] = 0; xw[p][r][f][165] = 0;
                xw[p][r][f][166] = 0; xw[p][r][f][167] = 0;
            }
    }

    float s[5][4];
#pragma unroll
    for (int f = 0; f < 5; ++f)
#pragma unroll
        for (int i = 0; i < 4; ++i) s[f][i] = 0.f;

    auto addS = [&](int zz) {
        float4 a = *(const float4*)(Ib + (size_t)zz * SLICE);
        float4 bb = *(const float4*)(Jb + (size_t)zz * SLICE);
        float av[4] = {a.x, a.y, a.z, a.w};
        float bv[4] = {bb.x, bb.y, bb.z, bb.w};
#pragma unroll
        for (int i = 0; i < 4; ++i) {
            float x = av[i], yv = bv[i];
            s[0][i] += x; s[1][i] += yv;
            s[2][i] += x * x; s[3][i] += yv * yv; s[4][i] += x * yv;
        }
    };

    int z0 = c * CHZ;
    for (int zz = (z0 - 4 < 0 ? 0 : z0 - 4); zz <= z0 + 4; ++zz) addS(zz);

#pragma unroll
    for (int dz = 0; dz < CHZ; ++dz) {
        int z = z0 + dz;
        int za = z + 5, zs = z - 4;
        bool ha = za < D, hs = zs >= 0;
        // issue next-tap loads early (latency hides under LDS work)
        float4 Az = ha ? *(const float4*)(Ib + (size_t)za * SLICE) : make_float4(0.f, 0.f, 0.f, 0.f);
        float4 Bz = ha ? *(const float4*)(Jb + (size_t)za * SLICE) : make_float4(0.f, 0.f, 0.f, 0.f);
        float4 As = hs ? *(const float4*)(Ib + (size_t)zs * SLICE) : make_float4(0.f, 0.f, 0.f, 0.f);
        float4 Bs = hs ? *(const float4*)(Jb + (size_t)zs * SLICE) : make_float4(0.f, 0.f, 0.f, 0.f);

        int p = dz & 1;
        // stage own 4 z-sums per field (bf16)
#pragma unroll
        for (int f = 0; f < 5; ++f) {
            uint2 w;
            w.x = bfpack2(s[f][0], s[f][1]);
            w.y = bfpack2(s[f][2], s[f][3]);
            *(uint2*)&xw[p][r][f][4 + x0] = w;
        }
        __syncthreads();

        // x-window: neighborhood [x0-4, x0+7] = L(4, bf16) + own(4, f32) + R(4, bf16)
        unsigned char* op = ob + (size_t)z * (H * FROW);
#pragma unroll
        for (int f = 0; f < 5; ++f) {
            uint2 Lv = *(const uint2*)&xw[p][r][f][x0];        // x0-4..x0-1
            uint2 Rv = *(const uint2*)&xw[p][r][f][x0 + 8];    // x0+4..x0+7
            float l0 = bflo(Lv.x), l1 = bfhi(Lv.x), l2 = bflo(Lv.y), l3 = bfhi(Lv.y);
            float r0 = bflo(Rv.x), r1 = bfhi(Rv.x), r2 = bflo(Rv.y), r3 = bfhi(Rv.y);
            float p0 = l0;
            float p1 = p0 + l1;
            float p2 = p1 + l2;
            float p3 = p2 + l3;
            float p4 = p3 + s[f][0];
            float p5 = p4 + s[f][1];
            float p6 = p5 + s[f][2];
            float p7 = p6 + s[f][3];
            float p8 = p7 + r0;
            float p9 = p8 + r1;
            float p10 = p9 + r2;
            float p11 = p10 + r3;
            *(unsigned int*)(op + f * W) = pk4(p8, p9 - p0, p10 - p1, p11 - p2);
        }
        // no second barrier: next dz stages into the other buffer

        // slide the z-window
        float ae[4] = {Az.x, Az.y, Az.z, Az.w};
        float be[4] = {Bz.x, Bz.y, Bz.z, Bz.w};
        float al[4] = {As.x, As.y, As.z, As.w};
        float bl[4] = {Bs.x, Bs.y, Bs.z, Bs.w};
#pragma unroll
        for (int i = 0; i < 4; ++i) {
            s[0][i] += ae[i] - al[i];
            s[1][i] += be[i] - bl[i];
            s[2][i] += ae[i] * ae[i] - al[i] * al[i];
            s[3][i] += be[i] * be[i] - bl[i] * bl[i];
            s[4][i] += ae[i] * be[i] - al[i] * bl[i];
        }
    }
}

// ---- pass 2: thin y-slide (4-wide, CHY=4) + cc + reduce ------------------
__global__ __launch_bounds__(TPB_Y) void pass_y(const unsigned char* __restrict__ A,
                                                double* __restrict__ partials) {
    int tid = threadIdx.x;
    int t = blockIdx.x * TPB_Y + tid;
    int xg = t % XGY4;
    int tup = t / XGY4;
    int yc = tup % NCHY;
    int z  = (tup / NCHY) % D;
    int b  = tup / (NCHY * D);
    int x0 = xg * 4;
    const unsigned char* __restrict__ base =
        A + (size_t)(b * D + z) * H * FROW + x0;
    int y0 = yc * CHY;

    float s[5][4];
#pragma unroll
    for (int f = 0; f < 5; ++f)
#pragma unroll
        for (int i = 0; i < 4; ++i) s[f][i] = 0.f;

    int ylo = y0 - 4 < 0 ? 0 : y0 - 4;
    int yhi = y0 + 4 > H - 1 ? H - 1 : y0 + 4;
    for (int yy = ylo; yy <= yhi; ++yy) {
        const unsigned char* rp = base + (size_t)yy * FROW;
#pragma unroll
        for (int f = 0; f < 5; ++f) {
            unsigned int v = *(const unsigned int*)(rp + f * W);
            float u[4]; up4(v, u);
#pragma unroll
            for (int i = 0; i < 4; ++i) s[f][i] += u[i];
        }
    }

    double acc = 0.0;
#pragma unroll
    for (int dy = 0; dy < CHY; ++dy) {
        int ye = y0 + dy + 5, yl = y0 + dy - 4;
        bool he = ye < H, hl = yl >= 0;
        unsigned int pe[5], pl[5];
        const unsigned char* pre = base + (size_t)(he ? ye : 0) * FROW;
        const unsigned char* prl = base + (size_t)(hl ? yl : 0) * FROW;
#pragma unroll
        for (int f = 0; f < 5; ++f) {
            pe[f] = he ? *(const unsigned int*)(pre + f * W) : 0u;
            pl[f] = hl ? *(const unsigned int*)(prl + f * W) : 0u;
        }

        float rowcc = 0.f;
#pragma unroll
        for (int i = 0; i < 4; ++i) {
            float Is = s[0][i], Js = s[1][i];
            float I2s = s[2][i], J2s = s[3][i], IJs = s[4][i];
            float tI = RW * Is;
            float cross = __builtin_fmaf(-tI, Js, IJs);
            float Iv    = __builtin_fmaf(-tI, Is, I2s);
            float Jv    = __builtin_fmaf(-(RW * Js), Js, J2s);
            float den   = __builtin_fmaf(Iv, Jv, 1e-5f);
            rowcc = __builtin_fmaf(cross * cross, __builtin_amdgcn_rcpf(den), rowcc);
        }
        acc += (double)rowcc;

#pragma unroll
        for (int f = 0; f < 5; ++f) {
            float ue[4], ul[4];
            up4(pe[f], ue); up4(pl[f], ul);
#pragma unroll
            for (int i = 0; i < 4; ++i) s[f][i] += ue[i] - ul[i];
        }
    }

    // deterministic block reduction
#pragma unroll
    for (int off = 32; off > 0; off >>= 1) acc += __shfl_down(acc, off);
    __shared__ double sm[TPB_Y / 64];
    if ((tid & 63) == 0) sm[tid >> 6] = acc;
    __syncthreads();
    if (tid == 0) {
        double tt = 0.0;
#pragma unroll
        for (int i = 0; i < TPB_Y / 64; ++i) tt += sm[i];
        partials[blockIdx.x] = tt;
    }
}

// ---- final deterministic reduce ------------------------------------------
__global__ __launch_bounds__(256) void finalize(const double* __restrict__ p,
                                                float* __restrict__ out) {
    double v = 0.0;
    for (int i = threadIdx.x; i < NBLK_Y; i += 256) v += p[i];
#pragma unroll
    for (int off = 32; off > 0; off >>= 1) v += __shfl_down(v, off);
    __shared__ double sm[4];
    int lane = threadIdx.x & 63, wid = threadIdx.x >> 6;
    if (lane == 0) sm[wid] = v;
    __syncthreads();
    if (threadIdx.x == 0) {
        double tt = 0.0;
#pragma unroll
        for (int i = 0; i < 4; ++i) tt += sm[i];
        out[0] = (float)(1.0 - tt / (double)((double)BATCH * (double)NVOX));
    }
}

extern "C" void kernel_launch(void* const* d_in, const int* in_sizes, int n_in,
                              void* d_out, int out_size, void* d_ws, size_t ws_size,
                              hipStream_t stream) {
    const float* I = (const float*)d_in[0];
    const float* J = (const float*)d_in[1];
    float* out = (float*)d_out;

    // ws: bufA (41 MB fp8) | partials (NBLK_Y f64)
    size_t bufsz = ((size_t)BATCH * 5 * NVOX + 255) / 256 * 256;
    unsigned char* bufA = (unsigned char*)d_ws;
    double* partials = (double*)(bufA + bufsz);

    pass_zx<<<NBLK_ZX, TPB_ZX, 0, stream>>>(I, J, bufA);
    pass_y<<<NBLK_Y, TPB_Y, 0, stream>>>(bufA, partials);
    finalize<<<1, 256, 0, stream>>>(partials, out);
}